// Round 8
// baseline (78.950 us; speedup 1.0000x reference)
//
#include <hip/hip_runtime.h>
#include <stdint.h>

#define BATCH 64
#define MDIM 512
#define KDIM 256
#define ROWS 64      // A rows per block (strip)
#define HCOLS 256    // cols per block (half)
#define NBLK 1024    // 64 batches x 8 strips x 2 halves

typedef __attribute__((ext_vector_type(8))) short short8;
typedef __attribute__((ext_vector_type(4))) float f32x4;
typedef __attribute__((ext_vector_type(4))) unsigned int u32x4;

// HW packed f32->bf16 RNE (no builtin on gfx950; single instr)
__device__ __forceinline__ unsigned int cvt_pk(float lo, float hi) {
  unsigned int r;
  asm("v_cvt_pk_bf16_f32 %0, %1, %2" : "=v"(r) : "v"(lo), "v"(hi));
  return r;
}

__device__ __forceinline__ float waveRedSum(float v) {
  v += __shfl_xor(v, 32);
  v += __shfl_xor(v, 16);
  v += __shfl_xor(v, 8);
  v += __shfl_xor(v, 4);
  v += __shfl_xor(v, 2);
  v += __shfl_xor(v, 1);
  return v;
}

// Block = (batch, 64-row A strip, 256-col half). 512 threads = 8 waves,
// wave tile 64x32. A staged to LDS once (bf16, unit-swizzled u^(row&7));
// ONE barrier total. B fragments gathered straight from global (dense:
// lane quads cover full 128B lines), cvt_pk'd in-register. K-loop has no
// LDS writes and no barriers -> compiler software-pipelines it freely.
__global__ __launch_bounds__(512, 8) void pot_gemm_reduce(
    const float* __restrict__ V, const float* __restrict__ Ae,
    float* __restrict__ part) {
  const int bid = blockIdx.x;
  const int lin = (bid & 7) * 128 + (bid >> 3);  // XCD swizzle: 8 batches/XCD
  const int b     = lin >> 4;
  const int strip = (lin >> 1) & 7;
  const int half  = lin & 1;

  const int tid  = threadIdx.x;
  const int w    = tid >> 6;       // wave 0..7
  const int lane = tid & 63;
  const int fr   = lane & 15;      // fragment row/col within 16
  const int fk   = lane >> 4;      // k-window 0..3
  const int frl  = fr & 7;

  __shared__ short As[ROWS][KDIM];  // 32 KiB bf16, unit-swizzle u^(row&7)
  __shared__ float nvs[ROWS];

  // ---- stage A strip (64x256 fp32 -> bf16) + row half-norms ----
  {
    const int row = tid >> 3;
    const int j   = tid & 7;
    const float* Ar = V + ((size_t)b * MDIM + strip * ROWS + row) * KDIM;
    float sq = 0.f;
#pragma unroll
    for (int i = 0; i < 4; ++i) {
      const int u = j * 4 + i;
      const float4* p = reinterpret_cast<const float4*>(Ar + u * 8);
      float4 x = p[0], y = p[1];
      u32x4 wv;
      wv[0] = cvt_pk(x.x, x.y); wv[1] = cvt_pk(x.z, x.w);
      wv[2] = cvt_pk(y.x, y.y); wv[3] = cvt_pk(y.z, y.w);
      sq += x.x * x.x + x.y * x.y + x.z * x.z + x.w * x.w;
      sq += y.x * y.x + y.y * y.y + y.z * y.z + y.w * y.w;
      *reinterpret_cast<u32x4*>(&As[row][(u ^ (row & 7)) * 8]) = wv;
    }
    sq += __shfl_xor(sq, 1);
    sq += __shfl_xor(sq, 2);
    sq += __shfl_xor(sq, 4);
    if (j == 0) nvs[row] = 0.5f * sq;
  }
  __syncthreads();   // the only barrier; As/nvs are read-only afterwards

  // ---- K-loop: B from global, A frags from LDS, no barriers ----
  const int gcb = half * HCOLS + w * 32;   // wave's global col base
  const float* B0 = Ae + ((size_t)b * MDIM + gcb + fr) * KDIM + fk * 8;
  const float* B1 = B0 + 16 * KDIM;

  f32x4 acc[4][2];
#pragma unroll
  for (int m = 0; m < 4; ++m)
#pragma unroll
    for (int n = 0; n < 2; ++n)
      acc[m][n] = (f32x4){0.f, 0.f, 0.f, 0.f};
  float sqb0 = 0.f, sqb1 = 0.f;

#pragma unroll
  for (int ks = 0; ks < 8; ++ks) {
    float4 x0 = *reinterpret_cast<const float4*>(B0 + ks * 32);
    float4 x1 = *reinterpret_cast<const float4*>(B0 + ks * 32 + 4);
    float4 y0 = *reinterpret_cast<const float4*>(B1 + ks * 32);
    float4 y1 = *reinterpret_cast<const float4*>(B1 + ks * 32 + 4);
    u32x4 t0, t1;
    t0[0] = cvt_pk(x0.x, x0.y); t0[1] = cvt_pk(x0.z, x0.w);
    t0[2] = cvt_pk(x1.x, x1.y); t0[3] = cvt_pk(x1.z, x1.w);
    t1[0] = cvt_pk(y0.x, y0.y); t1[1] = cvt_pk(y0.z, y0.w);
    t1[2] = cvt_pk(y1.x, y1.y); t1[3] = cvt_pk(y1.z, y1.w);
    sqb0 += x0.x * x0.x + x0.y * x0.y + x0.z * x0.z + x0.w * x0.w;
    sqb0 += x1.x * x1.x + x1.y * x1.y + x1.z * x1.z + x1.w * x1.w;
    sqb1 += y0.x * y0.x + y0.y * y0.y + y0.z * y0.z + y0.w * y0.w;
    sqb1 += y1.x * y1.x + y1.y * y1.y + y1.z * y1.z + y1.w * y1.w;
    short8 bf0 = *reinterpret_cast<short8*>(&t0);
    short8 bf1 = *reinterpret_cast<short8*>(&t1);

    const int su = ((4 * ks + fk) ^ frl) * 8;
    short8 af0 = *reinterpret_cast<const short8*>(&As[fr][su]);
    short8 af1 = *reinterpret_cast<const short8*>(&As[16 + fr][su]);
    short8 af2 = *reinterpret_cast<const short8*>(&As[32 + fr][su]);
    short8 af3 = *reinterpret_cast<const short8*>(&As[48 + fr][su]);

    acc[0][0] = __builtin_amdgcn_mfma_f32_16x16x32_bf16(af0, bf0, acc[0][0], 0, 0, 0);
    acc[0][1] = __builtin_amdgcn_mfma_f32_16x16x32_bf16(af0, bf1, acc[0][1], 0, 0, 0);
    acc[1][0] = __builtin_amdgcn_mfma_f32_16x16x32_bf16(af1, bf0, acc[1][0], 0, 0, 0);
    acc[1][1] = __builtin_amdgcn_mfma_f32_16x16x32_bf16(af1, bf1, acc[1][1], 0, 0, 0);
    acc[2][0] = __builtin_amdgcn_mfma_f32_16x16x32_bf16(af2, bf0, acc[2][0], 0, 0, 0);
    acc[2][1] = __builtin_amdgcn_mfma_f32_16x16x32_bf16(af2, bf1, acc[2][1], 0, 0, 0);
    acc[3][0] = __builtin_amdgcn_mfma_f32_16x16x32_bf16(af3, bf0, acc[3][0], 0, 0, 0);
    acc[3][1] = __builtin_amdgcn_mfma_f32_16x16x32_bf16(af3, bf1, acc[3][1], 0, 0, 0);
  }

  // ---- epilogue ----
  sqb0 += __shfl_xor(sqb0, 16); sqb0 += __shfl_xor(sqb0, 32);
  sqb1 += __shfl_xor(sqb1, 16); sqb1 += __shfl_xor(sqb1, 32);
  const float hc0 = 0.5f * sqb0;
  const float hc1 = 0.5f * sqb1;

  float hr[4][4];
#pragma unroll
  for (int m = 0; m < 4; ++m)
#pragma unroll
    for (int r = 0; r < 4; ++r)
      hr[m][r] = nvs[m * 16 + fk * 4 + r];

  const bool rowmask = (strip == 0) && (fk == 0);            // global row 0
  const bool colmask = (half == 0) && (w == 0) && (fr == 0); // global col 0
  const float k2 = -1.0e-3f * 1.4426950408889634f;           // -log2(e)/beta

  float s0p = 0.f, ctp = 0.f, rsp = 0.f, csp = 0.f;
#pragma unroll
  for (int m = 0; m < 4; ++m) {
#pragma unroll
    for (int n = 0; n < 2; ++n) {
#pragma unroll
      for (int r = 0; r < 4; ++r) {
        float Cv = hr[m][r] + (n ? hc1 : hc0) - acc[m][n][r];
        float T = exp2f(Cv * k2);
        s0p += T;
        ctp += Cv * T;
        if (m == 0 && r == 0) rsp += rowmask ? T : 0.f;
        if (n == 0)           csp += colmask ? T : 0.f;
      }
    }
  }

  s0p = waveRedSum(s0p);
  ctp = waveRedSum(ctp);
  rsp = waveRedSum(rsp);
  csp = waveRedSum(csp);
  if (lane == 0) {
    float* p = part + (((size_t)((b * 16 + strip * 2 + half)) * 8 + w)) * 4;
    p[0] = s0p; p[1] = ctp; p[2] = rsp; p[3] = csp;
  }
}

// 256 threads: 4 threads per batch, each sums 32 of the 128 wave-partials,
// shfl-combine, per-batch recurrence, LDS tree for the batch mean.
__global__ __launch_bounds__(256) void pot_finalize(
    const float* __restrict__ part, float* __restrict__ out) {
  __shared__ float dred[BATCH];
  const int t = threadIdx.x;
  const int batch = t >> 2;
  const int q = t & 3;

  float S0 = 0.f, CT = 0.f, RS = 0.f, CS = 0.f;
  const f32x4* p4 = reinterpret_cast<const f32x4*>(part);
#pragma unroll
  for (int i = 0; i < 32; ++i) {
    f32x4 v = p4[batch * 128 + q * 32 + i];
    S0 += v[0]; CT += v[1]; RS += v[2]; CS += v[3];
  }
  S0 += __shfl_xor(S0, 1); S0 += __shfl_xor(S0, 2);
  CT += __shfl_xor(CT, 1); CT += __shfl_xor(CT, 2);
  RS += __shfl_xor(RS, 1); RS += __shfl_xor(RS, 2);
  CS += __shfl_xor(CS, 1); CS += __shfl_xor(CS, 2);

  if (q == 0) {
    const float a0 = 1.0f / (float)MDIM;
    const float b0 = 1.0f / (float)MDIM;
    const float s  = (float)MDIM;
    float c = s / S0;
#pragma unroll
    for (int i = 0; i < 10; ++i) {
      float ka = fminf(a0 / (c * RS), 1.0f);
      float kb = fminf(b0 / (ka * c * CS), 1.0f);
      c = s * ka * kb / S0;
    }
    dred[batch] = c * CT;
  }
  __syncthreads();
  if (t < 64) {
    float D = waveRedSum(dred[t]);
    if (t == 0) out[0] = D * (1.0f / (float)BATCH);
  }
}

extern "C" void kernel_launch(void* const* d_in, const int* in_sizes, int n_in,
                              void* d_out, int out_size, void* d_ws, size_t ws_size,
                              hipStream_t stream) {
  const float* V  = (const float*)d_in[0];   // v_emb [64,512,256] f32
  const float* Ae = (const float*)d_in[1];   // a_emb [64,512,256] f32
  float* out  = (float*)d_out;
  float* part = (float*)d_ws;                // [1024][8][4] f32 = 128 KiB

  pot_gemm_reduce<<<dim3(NBLK), 512, 0, stream>>>(V, Ae, part);
  pot_finalize<<<1, 256, 0, stream>>>(part, out);
}

// Round 9
// 53.241 us; speedup vs baseline: 1.4829x; 1.4829x over previous
//
#include <hip/hip_runtime.h>
#include <stdint.h>

#define BATCH 64
#define MDIM 512
#define KDIM 256
#define ROWS 64      // A rows per block (strip)
#define HCOLS 256    // cols per block (half)
#define NBLK 1024    // 64 batches x 8 strips x 2 halves

typedef __attribute__((ext_vector_type(8))) short short8;
typedef __attribute__((ext_vector_type(4))) float f32x4;
typedef __attribute__((ext_vector_type(4))) unsigned int u32x4;

// HW packed f32->bf16 RNE (no builtin on gfx950; single instr)
__device__ __forceinline__ unsigned int cvt_pk(float lo, float hi) {
  unsigned int r;
  asm("v_cvt_pk_bf16_f32 %0, %1, %2" : "=v"(r) : "v"(lo), "v"(hi));
  return r;
}

__device__ __forceinline__ float waveRedSum(float v) {
  v += __shfl_xor(v, 32);
  v += __shfl_xor(v, 16);
  v += __shfl_xor(v, 8);
  v += __shfl_xor(v, 4);
  v += __shfl_xor(v, 2);
  v += __shfl_xor(v, 1);
  return v;
}

// Block = (batch, 64-row A strip, 256-col half). 512 threads = 8 waves,
// wave tile 64x32. A staged to LDS once (bf16, unit-swizzled u^(row&7));
// ONE barrier total. B fragments gathered straight from global (dense:
// lane quads cover full 128B lines), cvt_pk'd in-register. K-loop has no
// LDS writes and no barriers -> compiler software-pipelines it freely.
// launch_bounds(512,4): VGPR cap 128 (R8's (512,8) capped at 64 -> spilled).
__global__ __launch_bounds__(512, 4) void pot_gemm_reduce(
    const float* __restrict__ V, const float* __restrict__ Ae,
    float* __restrict__ part) {
  const int bid = blockIdx.x;
  const int lin = (bid & 7) * 128 + (bid >> 3);  // XCD swizzle: 8 batches/XCD
  const int b     = lin >> 4;
  const int strip = (lin >> 1) & 7;
  const int half  = lin & 1;

  const int tid  = threadIdx.x;
  const int w    = tid >> 6;       // wave 0..7
  const int lane = tid & 63;
  const int fr   = lane & 15;      // fragment row/col within 16
  const int fk   = lane >> 4;      // k-window 0..3
  const int frl  = fr & 7;

  __shared__ short As[ROWS][KDIM];  // 32 KiB bf16, unit-swizzle u^(row&7)
  __shared__ float nvs[ROWS];

  // ---- stage A strip (64x256 fp32 -> bf16) + row half-norms ----
  {
    const int row = tid >> 3;
    const int j   = tid & 7;
    const float* Ar = V + ((size_t)b * MDIM + strip * ROWS + row) * KDIM;
    float sq = 0.f;
#pragma unroll
    for (int i = 0; i < 4; ++i) {
      const int u = j * 4 + i;
      const float4* p = reinterpret_cast<const float4*>(Ar + u * 8);
      float4 x = p[0], y = p[1];
      u32x4 wv;
      wv[0] = cvt_pk(x.x, x.y); wv[1] = cvt_pk(x.z, x.w);
      wv[2] = cvt_pk(y.x, y.y); wv[3] = cvt_pk(y.z, y.w);
      sq += x.x * x.x + x.y * x.y + x.z * x.z + x.w * x.w;
      sq += y.x * y.x + y.y * y.y + y.z * y.z + y.w * y.w;
      *reinterpret_cast<u32x4*>(&As[row][(u ^ (row & 7)) * 8]) = wv;
    }
    sq += __shfl_xor(sq, 1);
    sq += __shfl_xor(sq, 2);
    sq += __shfl_xor(sq, 4);
    if (j == 0) nvs[row] = 0.5f * sq;
  }
  __syncthreads();   // the only barrier; As/nvs are read-only afterwards

  // ---- K-loop: B from global, A frags from LDS, no barriers ----
  const int gcb = half * HCOLS + w * 32;   // wave's global col base
  const float* B0 = Ae + ((size_t)b * MDIM + gcb + fr) * KDIM + fk * 8;
  const float* B1 = B0 + 16 * KDIM;

  f32x4 acc[4][2];
#pragma unroll
  for (int m = 0; m < 4; ++m)
#pragma unroll
    for (int n = 0; n < 2; ++n)
      acc[m][n] = (f32x4){0.f, 0.f, 0.f, 0.f};
  float sqb0 = 0.f, sqb1 = 0.f;

#pragma unroll
  for (int ks = 0; ks < 8; ++ks) {
    float4 x0 = *reinterpret_cast<const float4*>(B0 + ks * 32);
    float4 x1 = *reinterpret_cast<const float4*>(B0 + ks * 32 + 4);
    float4 y0 = *reinterpret_cast<const float4*>(B1 + ks * 32);
    float4 y1 = *reinterpret_cast<const float4*>(B1 + ks * 32 + 4);
    u32x4 t0, t1;
    t0[0] = cvt_pk(x0.x, x0.y); t0[1] = cvt_pk(x0.z, x0.w);
    t0[2] = cvt_pk(x1.x, x1.y); t0[3] = cvt_pk(x1.z, x1.w);
    t1[0] = cvt_pk(y0.x, y0.y); t1[1] = cvt_pk(y0.z, y0.w);
    t1[2] = cvt_pk(y1.x, y1.y); t1[3] = cvt_pk(y1.z, y1.w);
    sqb0 += x0.x * x0.x + x0.y * x0.y + x0.z * x0.z + x0.w * x0.w;
    sqb0 += x1.x * x1.x + x1.y * x1.y + x1.z * x1.z + x1.w * x1.w;
    sqb1 += y0.x * y0.x + y0.y * y0.y + y0.z * y0.z + y0.w * y0.w;
    sqb1 += y1.x * y1.x + y1.y * y1.y + y1.z * y1.z + y1.w * y1.w;
    short8 bf0 = *reinterpret_cast<short8*>(&t0);
    short8 bf1 = *reinterpret_cast<short8*>(&t1);

    const int su = ((4 * ks + fk) ^ frl) * 8;
    short8 af0 = *reinterpret_cast<const short8*>(&As[fr][su]);
    short8 af1 = *reinterpret_cast<const short8*>(&As[16 + fr][su]);
    short8 af2 = *reinterpret_cast<const short8*>(&As[32 + fr][su]);
    short8 af3 = *reinterpret_cast<const short8*>(&As[48 + fr][su]);

    acc[0][0] = __builtin_amdgcn_mfma_f32_16x16x32_bf16(af0, bf0, acc[0][0], 0, 0, 0);
    acc[0][1] = __builtin_amdgcn_mfma_f32_16x16x32_bf16(af0, bf1, acc[0][1], 0, 0, 0);
    acc[1][0] = __builtin_amdgcn_mfma_f32_16x16x32_bf16(af1, bf0, acc[1][0], 0, 0, 0);
    acc[1][1] = __builtin_amdgcn_mfma_f32_16x16x32_bf16(af1, bf1, acc[1][1], 0, 0, 0);
    acc[2][0] = __builtin_amdgcn_mfma_f32_16x16x32_bf16(af2, bf0, acc[2][0], 0, 0, 0);
    acc[2][1] = __builtin_amdgcn_mfma_f32_16x16x32_bf16(af2, bf1, acc[2][1], 0, 0, 0);
    acc[3][0] = __builtin_amdgcn_mfma_f32_16x16x32_bf16(af3, bf0, acc[3][0], 0, 0, 0);
    acc[3][1] = __builtin_amdgcn_mfma_f32_16x16x32_bf16(af3, bf1, acc[3][1], 0, 0, 0);
  }

  // ---- epilogue ----
  sqb0 += __shfl_xor(sqb0, 16); sqb0 += __shfl_xor(sqb0, 32);
  sqb1 += __shfl_xor(sqb1, 16); sqb1 += __shfl_xor(sqb1, 32);
  const float hc0 = 0.5f * sqb0;
  const float hc1 = 0.5f * sqb1;

  float hr[4][4];
#pragma unroll
  for (int m = 0; m < 4; ++m)
#pragma unroll
    for (int r = 0; r < 4; ++r)
      hr[m][r] = nvs[m * 16 + fk * 4 + r];

  const bool rowmask = (strip == 0) && (fk == 0);            // global row 0
  const bool colmask = (half == 0) && (w == 0) && (fr == 0); // global col 0
  const float k2 = -1.0e-3f * 1.4426950408889634f;           // -log2(e)/beta

  float s0p = 0.f, ctp = 0.f, rsp = 0.f, csp = 0.f;
#pragma unroll
  for (int m = 0; m < 4; ++m) {
#pragma unroll
    for (int n = 0; n < 2; ++n) {
#pragma unroll
      for (int r = 0; r < 4; ++r) {
        float Cv = hr[m][r] + (n ? hc1 : hc0) - acc[m][n][r];
        float T = exp2f(Cv * k2);
        s0p += T;
        ctp += Cv * T;
        if (m == 0 && r == 0) rsp += rowmask ? T : 0.f;
        if (n == 0)           csp += colmask ? T : 0.f;
      }
    }
  }

  s0p = waveRedSum(s0p);
  ctp = waveRedSum(ctp);
  rsp = waveRedSum(rsp);
  csp = waveRedSum(csp);
  if (lane == 0) {
    float* p = part + (((size_t)((b * 16 + strip * 2 + half)) * 8 + w)) * 4;
    p[0] = s0p; p[1] = ctp; p[2] = rsp; p[3] = csp;
  }
}

// 256 threads: 4 threads per batch, each sums 32 of the 128 wave-partials,
// shfl-combine, per-batch recurrence, LDS tree for the batch mean.
__global__ __launch_bounds__(256) void pot_finalize(
    const float* __restrict__ part, float* __restrict__ out) {
  __shared__ float dred[BATCH];
  const int t = threadIdx.x;
  const int batch = t >> 2;
  const int q = t & 3;

  float S0 = 0.f, CT = 0.f, RS = 0.f, CS = 0.f;
  const f32x4* p4 = reinterpret_cast<const f32x4*>(part);
#pragma unroll
  for (int i = 0; i < 32; ++i) {
    f32x4 v = p4[batch * 128 + q * 32 + i];
    S0 += v[0]; CT += v[1]; RS += v[2]; CS += v[3];
  }
  S0 += __shfl_xor(S0, 1); S0 += __shfl_xor(S0, 2);
  CT += __shfl_xor(CT, 1); CT += __shfl_xor(CT, 2);
  RS += __shfl_xor(RS, 1); RS += __shfl_xor(RS, 2);
  CS += __shfl_xor(CS, 1); CS += __shfl_xor(CS, 2);

  if (q == 0) {
    const float a0 = 1.0f / (float)MDIM;
    const float b0 = 1.0f / (float)MDIM;
    const float s  = (float)MDIM;
    float c = s / S0;
#pragma unroll
    for (int i = 0; i < 10; ++i) {
      float ka = fminf(a0 / (c * RS), 1.0f);
      float kb = fminf(b0 / (ka * c * CS), 1.0f);
      c = s * ka * kb / S0;
    }
    dred[batch] = c * CT;
  }
  __syncthreads();
  if (t < 64) {
    float D = waveRedSum(dred[t]);
    if (t == 0) out[0] = D * (1.0f / (float)BATCH);
  }
}

extern "C" void kernel_launch(void* const* d_in, const int* in_sizes, int n_in,
                              void* d_out, int out_size, void* d_ws, size_t ws_size,
                              hipStream_t stream) {
  const float* V  = (const float*)d_in[0];   // v_emb [64,512,256] f32
  const float* Ae = (const float*)d_in[1];   // a_emb [64,512,256] f32
  float* out  = (float*)d_out;
  float* part = (float*)d_ws;                // [1024][8][4] f32 = 128 KiB

  pot_gemm_reduce<<<dim3(NBLK), 512, 0, stream>>>(V, Ae, part);
  pot_finalize<<<1, 256, 0, stream>>>(part, out);
}